// Round 6
// baseline (1389.888 us; speedup 1.0000x reference)
//
#include <hip/hip_runtime.h>

#define NCOLS  8
#define BLOCK  256
#define NB     256          // streaming blocks for hist/scatter (1 per CU)
#define NBKT   1024         // row buckets (one accum block each)
#define LG2RPB 10
#define RPB    1024         // rows per bucket

// ---------- index-width autodetect (int32 vs int64 COO indices) ----------
// All index values < 2^20, so int64 data has zero high words. P(false pos) ~ 1e-96.
__device__ __forceinline__ int detect_is64(const void* p) {
    const unsigned* w = (const unsigned*)p;
    int is64 = 1;
    #pragma unroll
    for (int k = 0; k < 16; ++k) is64 &= (w[2 * k + 1] == 0u) ? 1 : 0;
    return is64;
}

__device__ __forceinline__ int load_idx(const void* p, int i, int is64) {
    return is64 ? (int)((const long long*)p)[i] : ((const int*)p)[i];
}

// ---------- k1: per-block row-bucket histogram ----------
__global__ __launch_bounds__(BLOCK) void k_hist(
    const void* __restrict__ rowp, int nnz, int chunk, unsigned* __restrict__ hist)
{
    __shared__ unsigned h[NBKT];
    const int is64 = detect_is64(rowp);
    for (int i = threadIdx.x; i < NBKT; i += BLOCK) h[i] = 0u;
    __syncthreads();
    const int beg = blockIdx.x * chunk;
    const int end = min(nnz, beg + chunk);
    for (int i = beg + threadIdx.x; i < end; i += BLOCK)
        atomicAdd(&h[load_idx(rowp, i, is64) >> LG2RPB], 1u);
    __syncthreads();
    unsigned* row = hist + (size_t)blockIdx.x * NBKT;
    for (int i = threadIdx.x; i < NBKT; i += BLOCK) row[i] = h[i];
}

// ---------- k2: fused transpose-prefix + bucket scan (single 1024-thread block) ----------
// Thread k owns bucket k. Pass 1: serial exclusive prefix over the NB block
// counts (loads are independent -> unrolled & pipelined; only the add chain is
// serial). Then LDS scan of bucket totals -> base[k].
__global__ __launch_bounds__(NBKT) void k_scan(
    unsigned* __restrict__ hist, unsigned* __restrict__ base)
{
    __shared__ unsigned s[NBKT];
    const int k = threadIdx.x;
    unsigned run = 0;
    #pragma unroll 8
    for (int b = 0; b < NB; ++b) {
        const size_t idx = (size_t)b * NBKT + k;
        unsigned t = hist[idx];
        hist[idx] = run;              // per-block exclusive prefix (within bucket k)
        run += t;
    }
    s[k] = run;                       // bucket total
    __syncthreads();
    for (int off = 1; off < NBKT; off <<= 1) {
        unsigned v = (k >= off) ? s[k - off] : 0u;
        __syncthreads();
        s[k] += v;
        __syncthreads();
    }
    base[k] = s[k] - run;             // exclusive bucket base
    if (k == NBKT - 1) base[NBKT] = s[k];
}

// ---------- k3: scatter into bucket-grouped order (LDS cursors, no global atomics) ----------
// record = (localrow<<20 | col, bits(val)), 8 bytes
__global__ __launch_bounds__(BLOCK) void k_scatter(
    const float* __restrict__ vals, const void* __restrict__ rowp,
    const void* __restrict__ colp, int nnz, int chunk,
    const unsigned* __restrict__ hist, const unsigned* __restrict__ base,
    uint2* __restrict__ records)
{
    __shared__ unsigned cur[NBKT];
    const int is64 = detect_is64(rowp);
    const unsigned* pref = hist + (size_t)blockIdx.x * NBKT;
    for (int i = threadIdx.x; i < NBKT; i += BLOCK) cur[i] = base[i] + pref[i];
    __syncthreads();
    const int beg = blockIdx.x * chunk;
    const int end = min(nnz, beg + chunk);
    for (int i = beg + threadIdx.x; i < end; i += BLOCK) {
        int r = load_idx(rowp, i, is64);
        int c = load_idx(colp, i, is64);
        float v = vals[i];
        unsigned pos = atomicAdd(&cur[r >> LG2RPB], 1u);
        records[pos] = make_uint2((((unsigned)r & (RPB - 1u)) << 20) | (unsigned)c,
                                  __float_as_uint(v));
    }
}

// ---------- k4: per-bucket gather + LDS accumulate + coalesced store ----------
__global__ __launch_bounds__(BLOCK) void k_accum1(
    const uint2* __restrict__ records, const unsigned* __restrict__ base,
    const float* __restrict__ field, float* __restrict__ out, int n)
{
    __shared__ float acc[NCOLS * RPB];        // 32 KB, transposed acc[j*RPB+lr]
    for (int i = threadIdx.x; i < NCOLS * RPB; i += BLOCK) acc[i] = 0.f;
    __syncthreads();
    const int b = blockIdx.x;
    const unsigned beg = base[b], end = base[b + 1];
    for (unsigned i = beg + threadIdx.x; i < end; i += BLOCK) {
        const uint2 rec = records[i];
        const unsigned col = rec.x & 0xFFFFFu;
        const unsigned lr  = rec.x >> 20;
        const float v = __uint_as_float(rec.y);
        const float4* f = (const float4*)(field + (size_t)col * NCOLS);
        const float4 f0 = f[0], f1 = f[1];
        atomicAdd(&acc[0 * RPB + lr], v * f0.x);
        atomicAdd(&acc[1 * RPB + lr], v * f0.y);
        atomicAdd(&acc[2 * RPB + lr], v * f0.z);
        atomicAdd(&acc[3 * RPB + lr], v * f0.w);
        atomicAdd(&acc[4 * RPB + lr], v * f1.x);
        atomicAdd(&acc[5 * RPB + lr], v * f1.y);
        atomicAdd(&acc[6 * RPB + lr], v * f1.z);
        atomicAdd(&acc[7 * RPB + lr], v * f1.w);
    }
    __syncthreads();
    // every output row written exactly once -> no pre-zero of out needed
    const size_t row0 = (size_t)b * RPB;
    for (int t = threadIdx.x; t < NCOLS * RPB; t += BLOCK) {
        int r = t >> 3, j = t & 7;
        size_t gr = row0 + (size_t)r;
        if (gr < (size_t)n) out[gr * NCOLS + j] = acc[j * RPB + r];
    }
}

// ---------- fallback: direct atomic scatter ----------
__global__ __launch_bounds__(BLOCK) void lap_zero_kernel(float4* __restrict__ out, int n4) {
    int i = blockIdx.x * BLOCK + threadIdx.x;
    if (i < n4) out[i] = make_float4(0.f, 0.f, 0.f, 0.f);
}

__global__ __launch_bounds__(BLOCK) void lap_spmm_atomic(
    const float* __restrict__ vals, const void* __restrict__ rowp,
    const void* __restrict__ colp, const float* __restrict__ field,
    float* __restrict__ out, int nnz)
{
    const int is64 = detect_is64(rowp);
    int i = blockIdx.x * BLOCK + threadIdx.x;
    if (i >= nnz) return;
    float v = vals[i];
    int r = load_idx(rowp, i, is64);
    int c = load_idx(colp, i, is64);
    const float4* f = (const float4*)(field + (size_t)c * NCOLS);
    float4 f0 = f[0], f1 = f[1];
    float* o = out + (size_t)r * NCOLS;
    unsafeAtomicAdd(o + 0, v * f0.x);
    unsafeAtomicAdd(o + 1, v * f0.y);
    unsafeAtomicAdd(o + 2, v * f0.z);
    unsafeAtomicAdd(o + 3, v * f0.w);
    unsafeAtomicAdd(o + 4, v * f1.x);
    unsafeAtomicAdd(o + 5, v * f1.y);
    unsafeAtomicAdd(o + 6, v * f1.z);
    unsafeAtomicAdd(o + 7, v * f1.w);
}

extern "C" void kernel_launch(void* const* d_in, const int* in_sizes, int n_in,
                              void* d_out, int out_size, void* d_ws, size_t ws_size,
                              hipStream_t stream) {
    const float* field = (const float*)d_in[0];
    const float* vals  = (const float*)d_in[1];
    const void*  rowp  = d_in[2];
    const void*  colp  = d_in[3];
    float* out = (float*)d_out;

    const int nnz = in_sizes[1];
    const int n   = out_size / NCOLS;
    char* ws = (char*)d_ws;

    // ws layout
    const size_t o_hist = 0;                                     // NB*NBKT u32 = 1 MB
    const size_t o_base = o_hist + (size_t)NB * NBKT * 4;        // NBKT+1 u32
    const size_t o_rec  = (o_base + (size_t)(NBKT + 1) * 4 + 255) & ~(size_t)255;
    const size_t need   = o_rec + (size_t)nnz * 8;

    if (n <= NBKT * RPB && n <= (1 << 20) && ws_size >= need) {
        unsigned* hist = (unsigned*)(ws + o_hist);
        unsigned* base = (unsigned*)(ws + o_base);
        uint2*    rec  = (uint2*)(ws + o_rec);

        const int chunk = (nnz + NB - 1) / NB;

        k_hist<<<NB, BLOCK, 0, stream>>>(rowp, nnz, chunk, hist);
        k_scan<<<1, NBKT, 0, stream>>>(hist, base);
        k_scatter<<<NB, BLOCK, 0, stream>>>(vals, rowp, colp, nnz, chunk, hist, base, rec);
        k_accum1<<<NBKT, BLOCK, 0, stream>>>(rec, base, field, out, n);
        return;
    }

    // fallback
    const int n4 = out_size / 4;
    lap_zero_kernel<<<(n4 + BLOCK - 1) / BLOCK, BLOCK, 0, stream>>>((float4*)out, n4);
    lap_spmm_atomic<<<(nnz + BLOCK - 1) / BLOCK, BLOCK, 0, stream>>>(
        vals, rowp, colp, field, out, nnz);
}